// Round 1
// baseline (466.563 us; speedup 1.0000x reference)
//
#include <hip/hip_runtime.h>
#include <hip/hip_bf16.h>
#include <cstddef>

#define GLOBAL_AS __attribute__((address_space(1)))
#define LDS_AS __attribute__((address_space(3)))

typedef __bf16 bf16_t;
typedef __bf16 bf16x8 __attribute__((ext_vector_type(8)));
typedef __bf16 bf16x4 __attribute__((ext_vector_type(4)));
typedef float f32x4 __attribute__((ext_vector_type(4)));

static constexpr int Tseq  = 4096;
static constexpr int Dd    = 1024;
static constexpr int Mrows = 8 * 4096;            // 32768
static constexpr int Ncat  = 2048;                // WB (1024) ++ WBf (1024)

// ---------------- cast u: f32 -> bf16, 4 elems/thread, exact grid ----------------
__global__ __launch_bounds__(256) void k_cast_u(const float* __restrict__ src,
                                                bf16_t* __restrict__ dst) {
    const int i = blockIdx.x * 256 + threadIdx.x;         // group of 4
    float4 v = reinterpret_cast<const float4*>(src)[i];
    bf16x4 o;
    o[0] = (__bf16)v.x; o[1] = (__bf16)v.y; o[2] = (__bf16)v.z; o[3] = (__bf16)v.w;
    reinterpret_cast<bf16x4*>(dst)[i] = o;
}

// ---------------- cast weights: Wcat[0:1024) = WB rows, [1024:2048) = WBf rows ----
__global__ __launch_bounds__(256) void k_cast_w(const float* __restrict__ WB,
                                                const float* __restrict__ WBf,
                                                bf16_t* __restrict__ dst) {
    const int i  = blockIdx.x * 256 + threadIdx.x;        // group of 4
    const int e4 = i * 4;
    const float* s = (e4 < 1024 * 1024) ? (WB + e4) : (WBf + (e4 - 1024 * 1024));
    float4 v = *reinterpret_cast<const float4*>(s);
    bf16x4 o;
    o[0] = (__bf16)v.x; o[1] = (__bf16)v.y; o[2] = (__bf16)v.z; o[3] = (__bf16)v.w;
    reinterpret_cast<bf16x4*>(dst)[i] = o;
}

// ---------------- GEMM: C[m,n] = sum_k A[m,k] * Bt[n,k], M=32768, N=2048, K=1024 --
// 128x128 tile, BK=64, 4 waves in 2x2 (each 64x64), mfma_f32_16x16x32_bf16.
// n < 1024  -> xf[m, n]            (epilogue overrides t==0)
// n >= 1024 -> xb[m-1, n-1024]     (epilogue overrides t==T-1; m==0 skipped)
__global__ __launch_bounds__(256, 2) void k_gemm(const bf16_t* __restrict__ A,
                                                 const bf16_t* __restrict__ Bt,
                                                 bf16_t* __restrict__ xf,
                                                 bf16_t* __restrict__ xb) {
    __shared__ bf16_t As[128 * 64];   // [row][k], 16 KB
    __shared__ bf16_t Bs[128 * 64];   // [n][k],   16 KB

    const int bid  = blockIdx.x;
    const int bcol = bid & 15;        // 16 col-tiles over Ncat=2048
    const int brow = bid >> 4;        // 256 row-tiles over M=32768
    const int tid  = threadIdx.x;
    const int wid  = tid >> 6;
    const int lane = tid & 63;
    const int wr = wid >> 1, wc = wid & 1;
    const int lane15 = lane & 15;
    const int laneK  = (lane >> 4) * 8;     // k-offset of this lane's 8 elems

    f32x4 acc[4][4] = {};

    const size_t aRow0 = (size_t)brow * 128;
    const size_t bRow0 = (size_t)bcol * 128;

    for (int k0 = 0; k0 < 1024; k0 += 64) {
        if (k0) __syncthreads();      // LDS reads of prev tile done before overwrite
        #pragma unroll
        for (int it = 0; it < 4; ++it) {
            const int l   = (wid * 4 + it) * 512 + lane * 8;   // linear bf16 idx in tile
            const int row = l >> 6;
            const int col = l & 63;
            const bf16_t* ga = A  + (aRow0 + row) * 1024 + k0 + col;
            const bf16_t* gb = Bt + (bRow0 + row) * 1024 + k0 + col;
            __builtin_amdgcn_global_load_lds((const GLOBAL_AS void*)ga,
                (LDS_AS void*)(As + (wid * 4 + it) * 512), 16, 0, 0);
            __builtin_amdgcn_global_load_lds((const GLOBAL_AS void*)gb,
                (LDS_AS void*)(Bs + (wid * 4 + it) * 512), 16, 0, 0);
        }
        __syncthreads();              // compiler drains vmcnt before s_barrier

        #pragma unroll
        for (int kk = 0; kk < 2; ++kk) {
            bf16x8 af[4], bfv[4];
            #pragma unroll
            for (int m = 0; m < 4; ++m)
                af[m] = *reinterpret_cast<const bf16x8*>(
                    As + (wr * 64 + m * 16 + lane15) * 64 + kk * 32 + laneK);
            #pragma unroll
            for (int n = 0; n < 4; ++n)
                bfv[n] = *reinterpret_cast<const bf16x8*>(
                    Bs + (wc * 64 + n * 16 + lane15) * 64 + kk * 32 + laneK);
            #pragma unroll
            for (int m = 0; m < 4; ++m)
                #pragma unroll
                for (int n = 0; n < 4; ++n)
                    acc[m][n] = __builtin_amdgcn_mfma_f32_16x16x32_bf16(
                        af[m], bfv[n], acc[m][n], 0, 0, 0);
        }
    }

    // C-write: D layout col = lane&15, row = (lane>>4)*4 + reg   [m89]
    const bool isF  = (bcol < 8);
    const int rbase = brow * 128 + wr * 64 + (lane >> 4) * 4;
    const int cbase = (isF ? bcol : bcol - 8) * 128 + wc * 64 + lane15;
    #pragma unroll
    for (int m = 0; m < 4; ++m) {
        #pragma unroll
        for (int j = 0; j < 4; ++j) {
            const int r = rbase + m * 16 + j;
            #pragma unroll
            for (int n = 0; n < 4; ++n) {
                const int c = cbase + n * 16;
                const __bf16 v = (__bf16)acc[m][n][j];
                if (isF)           xf[(size_t)r * 1024 + c]       = v;
                else if (r >= 1)   xb[(size_t)(r - 1) * 1024 + c] = v;
            }
        }
    }
}

// ---------------- epilogue: one block per row ------------------------------------
// gamma = sigmoid(xf.w1 + xb.w2 + b); y = g*(xf+xb) + (1-g)*u; final = sigmoid(y.Wc)
__global__ __launch_bounds__(256) void k_epi(const float* __restrict__ u,
                                             const bf16_t* __restrict__ xf,
                                             const bf16_t* __restrict__ xb,
                                             const float* __restrict__ w1,
                                             const float* __restrict__ w2,
                                             const float* __restrict__ bb,
                                             const float* __restrict__ Wc,
                                             float* __restrict__ y,
                                             float* __restrict__ gout,
                                             float* __restrict__ fout) {
    const int m   = blockIdx.x;           // row 0..32767
    const int t   = m & (Tseq - 1);
    const int tid = threadIdx.x;
    const int j0  = tid * 4;
    const size_t rb = (size_t)m * Dd;

    const float4 uu = *reinterpret_cast<const float4*>(u + rb + j0);

    float xfl[4], xbl[4];
    if (t == 0) {
        xfl[0] = uu.x; xfl[1] = uu.y; xfl[2] = uu.z; xfl[3] = uu.w;
    } else {
        bf16x4 v = *reinterpret_cast<const bf16x4*>(xf + rb + j0);
        #pragma unroll
        for (int j = 0; j < 4; ++j) xfl[j] = (float)v[j];
    }
    if (t == Tseq - 1) {
        xbl[0] = uu.x; xbl[1] = uu.y; xbl[2] = uu.z; xbl[3] = uu.w;
    } else {
        bf16x4 v = *reinterpret_cast<const bf16x4*>(xb + rb + j0);
        #pragma unroll
        for (int j = 0; j < 4; ++j) xbl[j] = (float)v[j];
    }

    const float4 w1v = *reinterpret_cast<const float4*>(w1 + j0);
    const float4 w2v = *reinterpret_cast<const float4*>(w2 + j0);

    float part = xfl[0] * w1v.x + xfl[1] * w1v.y + xfl[2] * w1v.z + xfl[3] * w1v.w
               + xbl[0] * w2v.x + xbl[1] * w2v.y + xbl[2] * w2v.z + xbl[3] * w2v.w;
    #pragma unroll
    for (int off = 32; off >= 1; off >>= 1) part += __shfl_xor(part, off);

    __shared__ float red1[4];
    __shared__ float red2[4];
    if ((tid & 63) == 0) red1[tid >> 6] = part;
    __syncthreads();
    const float logit = red1[0] + red1[1] + red1[2] + red1[3] + bb[0];
    const float g = 1.0f / (1.0f + __expf(-logit));

    float4 yv;
    yv.x = g * (xfl[0] + xbl[0]) + (1.0f - g) * uu.x;
    yv.y = g * (xfl[1] + xbl[1]) + (1.0f - g) * uu.y;
    yv.z = g * (xfl[2] + xbl[2]) + (1.0f - g) * uu.z;
    yv.w = g * (xfl[3] + xbl[3]) + (1.0f - g) * uu.w;
    *reinterpret_cast<float4*>(y + rb + j0) = yv;

    const float4 wcv = *reinterpret_cast<const float4*>(Wc + j0);
    float p2 = yv.x * wcv.x + yv.y * wcv.y + yv.z * wcv.z + yv.w * wcv.w;
    #pragma unroll
    for (int off = 32; off >= 1; off >>= 1) p2 += __shfl_xor(p2, off);
    if ((tid & 63) == 0) red2[tid >> 6] = p2;
    __syncthreads();
    if (tid == 0) {
        const float fl = red2[0] + red2[1] + red2[2] + red2[3];
        gout[m] = g;
        fout[m] = 1.0f / (1.0f + __expf(-fl));
    }
}

extern "C" void kernel_launch(void* const* d_in, const int* in_sizes, int n_in,
                              void* d_out, int out_size, void* d_ws, size_t ws_size,
                              hipStream_t stream) {
    const float* u   = (const float*)d_in[0];
    // d_in[1] = WA (dead), d_in[3] = WAf (dead)
    const float* WB  = (const float*)d_in[2];
    const float* WBf = (const float*)d_in[4];
    const float* w1  = (const float*)d_in[5];
    const float* w2  = (const float*)d_in[6];
    const float* bb  = (const float*)d_in[7];
    const float* Wc  = (const float*)d_in[8];

    char* ws = (char*)d_ws;
    bf16_t* u16  = (bf16_t*)(ws);                         //  64 MiB
    bf16_t* wcat = (bf16_t*)(ws + 67108864);              //   4 MiB
    bf16_t* xfw  = (bf16_t*)(ws + 71303168);              //  64 MiB
    bf16_t* xbw  = (bf16_t*)(ws + 138412032);             //  64 MiB (ends 205,520,896)

    float* y    = (float*)d_out;
    float* gout = y + (size_t)Mrows * Dd;                 // 33,554,432
    float* fout = gout + Mrows;                           // +32,768

    // 1) casts
    k_cast_u<<<dim3(32768), dim3(256), 0, stream>>>(u, u16);      // 32768*256*4 = 33,554,432
    k_cast_w<<<dim3(2048),  dim3(256), 0, stream>>>(WB, WBf, wcat);

    // 2) GEMM: (M/128)*(Ncat/128) = 256*16 = 4096 blocks
    k_gemm<<<dim3(4096), dim3(256), 0, stream>>>(u16, wcat, xfw, xbw);

    // 3) fused epilogue: one block per row
    k_epi<<<dim3(Mrows), dim3(256), 0, stream>>>(u, xfw, xbw, w1, w2, bb, Wc,
                                                 y, gout, fout);
}

// Round 3
// 444.910 us; speedup vs baseline: 1.0487x; 1.0487x over previous
//
#include <hip/hip_runtime.h>
#include <hip/hip_bf16.h>
#include <cstddef>

#define GLOBAL_AS __attribute__((address_space(1)))
#define LDS_AS __attribute__((address_space(3)))

typedef __bf16 bf16_t;
typedef __bf16 bf16x8 __attribute__((ext_vector_type(8)));
typedef __bf16 bf16x4 __attribute__((ext_vector_type(4)));
typedef float f32x4 __attribute__((ext_vector_type(4)));

static constexpr int Tseq  = 4096;
static constexpr int Dd    = 1024;
static constexpr int Mrows = 8 * 4096;            // 32768

// ---------------- cast u: f32 -> bf16, 4 elems/thread ----------------
__global__ __launch_bounds__(256) void k_cast_u(const float* __restrict__ src,
                                                bf16_t* __restrict__ dst) {
    const int i = blockIdx.x * 256 + threadIdx.x;
    float4 v = reinterpret_cast<const float4*>(src)[i];
    bf16x4 o;
    o[0] = (__bf16)v.x; o[1] = (__bf16)v.y; o[2] = (__bf16)v.z; o[3] = (__bf16)v.w;
    reinterpret_cast<bf16x4*>(dst)[i] = o;
}

// ---------------- cast weights: Wcat = WB rows ++ WBf rows ----------------
__global__ __launch_bounds__(256) void k_cast_w(const float* __restrict__ WB,
                                                const float* __restrict__ WBf,
                                                bf16_t* __restrict__ dst) {
    const int i  = blockIdx.x * 256 + threadIdx.x;
    const int e4 = i * 4;
    const float* s = (e4 < 1024 * 1024) ? (WB + e4) : (WBf + (e4 - 1024 * 1024));
    float4 v = *reinterpret_cast<const float4*>(s);
    bf16x4 o;
    o[0] = (__bf16)v.x; o[1] = (__bf16)v.y; o[2] = (__bf16)v.z; o[3] = (__bf16)v.w;
    reinterpret_cast<bf16x4*>(dst)[i] = o;
}

// ---------------- 256x256x64 8-phase pipelined GEMM --------------------------
// C[m,n] = sum_k A[m,k]*Bt[n,k]; M=32768, N=2048, K=1024.
// 512 thr = 8 waves (4 Mq x 2 Nq). Per-wave out: 64 rows (32 in each A-half)
// x 128 cols (64 in each B-half). Phases per K-tile: (A0B0)(A1B0)(A1B1)(A0B1),
// staging next tile's halves A0,B0,A1,B1 one per phase; counted vmcnt(4).
// LDS 128 KiB: [buf2][A|B][half2][128 rows][128 B], XOR-swizzle (row&7)<<4.
__global__ __launch_bounds__(512, 2) void k_gemm(const bf16_t* __restrict__ A,
                                                 const bf16_t* __restrict__ Bt,
                                                 bf16_t* __restrict__ xf,
                                                 bf16_t* __restrict__ xb) {
    __shared__ __align__(16) char sm[131072];

    const int tid  = threadIdx.x;
    const int wid  = tid >> 6;
    const int lane = tid & 63;
    const int lane15 = lane & 15;
    const int g16  = (lane >> 4) * 16;     // byte offset from k-group
    const int wmq  = wid >> 1;             // 0..3
    const int wnq  = wid & 1;              // 0..1

    // bijective XCD swizzle (nwg=1024, 8 XCDs): XCD x gets contiguous brow range
    const int bid0 = blockIdx.x;
    const int swzb = (bid0 & 7) * 128 + (bid0 >> 3);
    const int bcol = swzb & 7;             // 8 col tiles of 256 over Ncat=2048
    const int brow = swzb >> 3;            // 128 row tiles of 256

    // staging source: dest byte L = tid*16 (+8192); logical = L ^ ((row&7)<<4)
    const int srow = tid >> 3;                        // 0..63
    const int scol = ((tid & 7) ^ (srow & 7)) * 8;    // elems
    const bf16_t* gA = A  + ((size_t)brow * 256 + srow) * 1024 + scol;
    const bf16_t* gB = Bt + ((size_t)bcol * 256 + srow) * 1024 + scol;

    char* const smw = sm + wid * 1024;     // per-wave stage dest (wave-uniform)

    f32x4 acc[2][2][2][4] = {};            // [mh][mi][nh][ni]
    bf16x8 afr[2][2], bfr[4][2];           // [mi|ni][kk]

#define STAGE(bufb, isA, h, kt1) do {                                          \
    const bf16_t* _s = ((isA) ? gA : gB) + (size_t)(h) * 131072 + (kt1) * 64;  \
    char* _l = smw + (bufb) * 65536 + ((isA) ? 0 : 32768) + (h) * 16384;       \
    __builtin_amdgcn_global_load_lds((const GLOBAL_AS void*)_s,                \
                                     (LDS_AS void*)_l, 16, 0, 0);              \
    __builtin_amdgcn_global_load_lds((const GLOBAL_AS void*)(_s + 65536),      \
                                     (LDS_AS void*)(_l + 8192), 16, 0, 0);     \
} while (0)

#define RD_A(bufb, mhh) do {                                                   \
    _Pragma("unroll") for (int mi = 0; mi < 2; ++mi) {                         \
      const int rr = wmq * 32 + mi * 16 + lane15;                              \
      const char* _p = sm + (bufb) * 65536 + (mhh) * 16384 + rr * 128;         \
      const int sz = (rr & 7) << 4;                                            \
      _Pragma("unroll") for (int kk = 0; kk < 2; ++kk)                         \
        afr[mi][kk] = *reinterpret_cast<const bf16x8*>(_p + ((kk * 64 + g16) ^ sz)); \
    } } while (0)

#define RD_B(bufb, nhh) do {                                                   \
    _Pragma("unroll") for (int ni = 0; ni < 4; ++ni) {                         \
      const int rr = wnq * 64 + ni * 16 + lane15;                              \
      const char* _p = sm + (bufb) * 65536 + 32768 + (nhh) * 16384 + rr * 128; \
      const int sz = (rr & 7) << 4;                                            \
      _Pragma("unroll") for (int kk = 0; kk < 2; ++kk)                         \
        bfr[ni][kk] = *reinterpret_cast<const bf16x8*>(_p + ((kk * 64 + g16) ^ sz)); \
    } } while (0)

#define MM(MH, NH) do {                                                        \
    __builtin_amdgcn_s_setprio(1);                                             \
    _Pragma("unroll") for (int kk = 0; kk < 2; ++kk)                           \
    _Pragma("unroll") for (int mi = 0; mi < 2; ++mi)                           \
    _Pragma("unroll") for (int ni = 0; ni < 4; ++ni)                           \
      acc[MH][mi][NH][ni] = __builtin_amdgcn_mfma_f32_16x16x32_bf16(           \
          afr[mi][kk], bfr[ni][kk], acc[MH][mi][NH][ni], 0, 0, 0);             \
    __builtin_amdgcn_s_setprio(0);                                             \
} while (0)

#define BARM() asm volatile("s_barrier" ::: "memory")

    // prologue: stage all 4 halves of tile 0 (issue order A0,B0,A1,B1)
    STAGE(0, 1, 0, 0);
    STAGE(0, 0, 0, 0);
    STAGE(0, 1, 1, 0);
    STAGE(0, 0, 1, 0);
    asm volatile("s_waitcnt vmcnt(4)" ::: "memory");   // A0,B0 done
    BARM();

#pragma unroll 2
    for (int t = 0; t < 16; ++t) {
        const int buf = t & 1;
        const bool pf = t < 15;
        const int k1 = t + 1;
        // ---- P0: A0 x B0; stage A0(t+1)
        RD_A(buf, 0); RD_B(buf, 0);
        if (pf) STAGE(buf ^ 1, 1, 0, k1);
        __builtin_amdgcn_s_barrier();
        MM(0, 0);
        if (pf) { asm volatile("s_waitcnt vmcnt(4)" ::: "memory"); }   // A1(t) done
        else    { asm volatile("s_waitcnt vmcnt(2)" ::: "memory"); }
        BARM();
        // ---- P1: A1 x B0; stage B0(t+1)
        RD_A(buf, 1);
        if (pf) STAGE(buf ^ 1, 0, 0, k1);
        __builtin_amdgcn_s_barrier();
        MM(1, 0);
        if (pf) { asm volatile("s_waitcnt vmcnt(4)" ::: "memory"); }   // B1(t) done
        else    { asm volatile("s_waitcnt vmcnt(0)" ::: "memory"); }
        BARM();
        // ---- P2: A1 x B1; stage A1(t+1)
        RD_B(buf, 1);
        if (pf) STAGE(buf ^ 1, 1, 1, k1);
        __builtin_amdgcn_s_barrier();
        MM(1, 1);
        BARM();
        // ---- P3: A0 x B1; stage B1(t+1)
        RD_A(buf, 0);
        if (pf) STAGE(buf ^ 1, 0, 1, k1);
        __builtin_amdgcn_s_barrier();
        MM(0, 1);
        if (pf) { asm volatile("s_waitcnt vmcnt(4)" ::: "memory"); }   // A0,B0(t+1) done
        BARM();
    }

    // C-write. n<1024 -> xf[m,n]; n>=1024 -> xb[m-1,n-1024] (skip m==0).
    const bool isF  = bcol < 4;           // block-uniform
    const int rbase = brow * 256 + wmq * 32 + (lane >> 4) * 4;
    const int cb0   = bcol * 256 + wnq * 64 + lane15;
    #pragma unroll
    for (int mh = 0; mh < 2; ++mh)
    #pragma unroll
    for (int mi = 0; mi < 2; ++mi)
    #pragma unroll
    for (int j = 0; j < 4; ++j) {
        const int r = rbase + mh * 128 + mi * 16 + j;
        #pragma unroll
        for (int nh = 0; nh < 2; ++nh)
        #pragma unroll
        for (int ni = 0; ni < 4; ++ni) {
            const int c = cb0 + nh * 128 + ni * 16;
            const __bf16 v = (__bf16)acc[mh][mi][nh][ni][j];
            if (isF)         xf[(size_t)r * 1024 + c] = v;
            else if (r >= 1) xb[(size_t)(r - 1) * 1024 + (c - 1024)] = v;
        }
    }
#undef STAGE
#undef RD_A
#undef RD_B
#undef MM
#undef BARM
}

// ---------------- epilogue: one WAVE per row (no LDS, no barriers) -----------
__global__ __launch_bounds__(256) void k_epi(const float* __restrict__ u,
                                             const bf16_t* __restrict__ xf,
                                             const bf16_t* __restrict__ xb,
                                             const float* __restrict__ w1,
                                             const float* __restrict__ w2,
                                             const float* __restrict__ bb,
                                             const float* __restrict__ Wc,
                                             float* __restrict__ y,
                                             float* __restrict__ gout,
                                             float* __restrict__ fout) {
    const int lane = threadIdx.x & 63;
    const int row  = blockIdx.x * 4 + (threadIdx.x >> 6);
    const int t    = row & (Tseq - 1);
    const size_t rb = (size_t)row * Dd;

    float uv[16], xfv[16], xbv[16];
    #pragma unroll
    for (int j = 0; j < 2; ++j) {
        const int e = j * 512 + lane * 8;
        const float4 u0 = *reinterpret_cast<const float4*>(u + rb + e);
        const float4 u1 = *reinterpret_cast<const float4*>(u + rb + e + 4);
        uv[j*8+0] = u0.x; uv[j*8+1] = u0.y; uv[j*8+2] = u0.z; uv[j*8+3] = u0.w;
        uv[j*8+4] = u1.x; uv[j*8+5] = u1.y; uv[j*8+6] = u1.z; uv[j*8+7] = u1.w;
        const bf16x8 f8 = *reinterpret_cast<const bf16x8*>(xf + rb + e);
        const bf16x8 b8 = *reinterpret_cast<const bf16x8*>(xb + rb + e);
        #pragma unroll
        for (int i = 0; i < 8; ++i) { xfv[j*8+i] = (float)f8[i]; xbv[j*8+i] = (float)b8[i]; }
    }
    if (t == 0) {
        #pragma unroll
        for (int i = 0; i < 16; ++i) xfv[i] = uv[i];
    }
    if (t == Tseq - 1) {
        #pragma unroll
        for (int i = 0; i < 16; ++i) xbv[i] = uv[i];
    }

    float part = 0.0f;
    #pragma unroll
    for (int j = 0; j < 2; ++j) {
        const int e = j * 512 + lane * 8;
        const float4 a0 = *reinterpret_cast<const float4*>(w1 + e);
        const float4 a1 = *reinterpret_cast<const float4*>(w1 + e + 4);
        const float4 c0 = *reinterpret_cast<const float4*>(w2 + e);
        const float4 c1 = *reinterpret_cast<const float4*>(w2 + e + 4);
        part += xfv[j*8+0]*a0.x + xfv[j*8+1]*a0.y + xfv[j*8+2]*a0.z + xfv[j*8+3]*a0.w
              + xfv[j*8+4]*a1.x + xfv[j*8+5]*a1.y + xfv[j*8+6]*a1.z + xfv[j*8+7]*a1.w
              + xbv[j*8+0]*c0.x + xbv[j*8+1]*c0.y + xbv[j*8+2]*c0.z + xbv[j*8+3]*c0.w
              + xbv[j*8+4]*c1.x + xbv[j*8+5]*c1.y + xbv[j*8+6]*c1.z + xbv[j*8+7]*c1.w;
    }
    #pragma unroll
    for (int off = 32; off >= 1; off >>= 1) part += __shfl_xor(part, off);
    const float g = 1.0f / (1.0f + __expf(-(part + bb[0])));

    float p2 = 0.0f;
    #pragma unroll
    for (int j = 0; j < 2; ++j) {
        const int e = j * 512 + lane * 8;
        float4 y0, y1;
        y0.x = g * (xfv[j*8+0] + xbv[j*8+0]) + (1.0f - g) * uv[j*8+0];
        y0.y = g * (xfv[j*8+1] + xbv[j*8+1]) + (1.0f - g) * uv[j*8+1];
        y0.z = g * (xfv[j*8+2] + xbv[j*8+2]) + (1.0f - g) * uv[j*8+2];
        y0.w = g * (xfv[j*8+3] + xbv[j*8+3]) + (1.0f - g) * uv[j*8+3];
        y1.x = g * (xfv[j*8+4] + xbv[j*8+4]) + (1.0f - g) * uv[j*8+4];
        y1.y = g * (xfv[j*8+5] + xbv[j*8+5]) + (1.0f - g) * uv[j*8+5];
        y1.z = g * (xfv[j*8+6] + xbv[j*8+6]) + (1.0f - g) * uv[j*8+6];
        y1.w = g * (xfv[j*8+7] + xbv[j*8+7]) + (1.0f - g) * uv[j*8+7];
        *reinterpret_cast<float4*>(y + rb + e)     = y0;
        *reinterpret_cast<float4*>(y + rb + e + 4) = y1;
        const float4 wc0 = *reinterpret_cast<const float4*>(Wc + e);
        const float4 wc1 = *reinterpret_cast<const float4*>(Wc + e + 4);
        p2 += y0.x*wc0.x + y0.y*wc0.y + y0.z*wc0.z + y0.w*wc0.w
            + y1.x*wc1.x + y1.y*wc1.y + y1.z*wc1.z + y1.w*wc1.w;
    }
    #pragma unroll
    for (int off = 32; off >= 1; off >>= 1) p2 += __shfl_xor(p2, off);
    if (lane == 0) {
        gout[row] = g;
        fout[row] = 1.0f / (1.0f + __expf(-p2));
    }
}

extern "C" void kernel_launch(void* const* d_in, const int* in_sizes, int n_in,
                              void* d_out, int out_size, void* d_ws, size_t ws_size,
                              hipStream_t stream) {
    const float* u   = (const float*)d_in[0];
    const float* WB  = (const float*)d_in[2];
    const float* WBf = (const float*)d_in[4];
    const float* w1  = (const float*)d_in[5];
    const float* w2  = (const float*)d_in[6];
    const float* bb  = (const float*)d_in[7];
    const float* Wc  = (const float*)d_in[8];

    char* ws = (char*)d_ws;
    bf16_t* u16  = (bf16_t*)(ws);                         //  64 MiB
    bf16_t* wcat = (bf16_t*)(ws + 67108864);              //   4 MiB
    bf16_t* xfw  = (bf16_t*)(ws + 71303168);              //  64 MiB
    bf16_t* xbw  = (bf16_t*)(ws + 138412032);             //  64 MiB

    float* y    = (float*)d_out;
    float* gout = y + (size_t)Mrows * Dd;
    float* fout = gout + Mrows;

    k_cast_u<<<dim3(32768), dim3(256), 0, stream>>>(u, u16);
    k_cast_w<<<dim3(2048),  dim3(256), 0, stream>>>(WB, WBf, wcat);

    // (M/256)*(Ncat/256) = 128*8 = 1024 blocks, 512 threads
    k_gemm<<<dim3(1024), dim3(512), 0, stream>>>(u16, wcat, xfw, xbw);

    // one wave per row, 4 rows per block
    k_epi<<<dim3(Mrows / 4), dim3(256), 0, stream>>>(u, xfw, xbw, w1, w2, bb, Wc,
                                                     y, gout, fout);
}

// Round 5
// 425.160 us; speedup vs baseline: 1.0974x; 1.0465x over previous
//
#include <hip/hip_runtime.h>
#include <hip/hip_bf16.h>
#include <cstddef>

#define GLOBAL_AS __attribute__((address_space(1)))
#define LDS_AS __attribute__((address_space(3)))

typedef __bf16 bf16_t;
typedef __bf16 bf16x8 __attribute__((ext_vector_type(8)));
typedef __bf16 bf16x4 __attribute__((ext_vector_type(4)));
typedef float f32x4 __attribute__((ext_vector_type(4)));

static constexpr int Tseq  = 4096;
static constexpr int Dd    = 1024;
static constexpr int Mrows = 8 * 4096;            // 32768
static constexpr int UGRP  = 8388608;             // u float4-groups (32M/4)

// ---------------- fused cast: u -> u16, (WB,WBf) -> wcat --------------------
__global__ __launch_bounds__(256) void k_prep(const float* __restrict__ u,
                                              const float* __restrict__ WB,
                                              const float* __restrict__ WBf,
                                              bf16_t* __restrict__ u16,
                                              bf16_t* __restrict__ wcat) {
    const int i = blockIdx.x * 256 + threadIdx.x;
    if (i < UGRP) {
        float4 v = reinterpret_cast<const float4*>(u)[i];
        bf16x4 o;
        o[0] = (__bf16)v.x; o[1] = (__bf16)v.y; o[2] = (__bf16)v.z; o[3] = (__bf16)v.w;
        reinterpret_cast<bf16x4*>(u16)[i] = o;
    } else {
        const int j  = i - UGRP;                  // 0 .. 524287
        const int e4 = j * 4;
        const float* s = (e4 < 1024 * 1024) ? (WB + e4) : (WBf + (e4 - 1024 * 1024));
        float4 v = *reinterpret_cast<const float4*>(s);
        bf16x4 o;
        o[0] = (__bf16)v.x; o[1] = (__bf16)v.y; o[2] = (__bf16)v.z; o[3] = (__bf16)v.w;
        reinterpret_cast<bf16x4*>(wcat)[j] = o;
    }
}

// ---------------- 256x256x64 pipelined GEMM --------------------------------
// C[m,n] = sum_k A[m,k]*Bt[n,k]; M=32768, N=2048, K=1024.
// 512 thr = 8 waves (4 Mq x 2 Nq); per-wave 64x128 out.
// Quadrants per K-tile: (A0B0)(A1B0)(A1B1)(A0B1); A0 fragments persist
// P0->P3 (no re-read). LDS reads: 24 b128/wave/tile (unique data only).
// LDS 128 KiB: [buf2][A|B][half2][128 rows][128 B], XOR-swizzle (row&7)<<4.
__global__ __launch_bounds__(512, 2) void k_gemm(const bf16_t* __restrict__ A,
                                                 const bf16_t* __restrict__ Bt,
                                                 bf16_t* __restrict__ xf,
                                                 bf16_t* __restrict__ xb) {
    __shared__ __align__(16) char sm[131072];

    const int tid  = threadIdx.x;
    const int wid  = tid >> 6;
    const int lane = tid & 63;
    const int lane15 = lane & 15;
    const int g16  = (lane >> 4) * 16;     // byte offset from k-group
    const int wmq  = wid >> 1;             // 0..3
    const int wnq  = wid & 1;              // 0..1

    // bijective XCD swizzle (nwg=1024, 8 XCDs)
    const int bid0 = blockIdx.x;
    const int swzb = (bid0 & 7) * 128 + (bid0 >> 3);
    const int bcol = swzb & 7;             // 8 col tiles of 256 over Ncat=2048
    const int brow = swzb >> 3;            // 128 row tiles of 256

    // staging source: dest byte L = tid*16 (+8192); logical = L ^ ((row&7)<<4)
    const int srow = tid >> 3;                        // 0..63
    const int scol = ((tid & 7) ^ (srow & 7)) * 8;    // elems
    const bf16_t* gA = A  + ((size_t)brow * 256 + srow) * 1024 + scol;
    const bf16_t* gB = Bt + ((size_t)bcol * 256 + srow) * 1024 + scol;

    char* const smw = sm + wid * 1024;     // per-wave stage dest (wave-uniform)

    f32x4 acc[2][2][2][4] = {};            // [mh][mi][nh][ni]
    bf16x8 afr[2][2][2];                   // [mh][mi][kk]  (A0 persists P0->P3)
    bf16x8 bfr[4][2];                      // [ni][kk]

#define STAGE(bufb, isA, h, kt1) do {                                          \
    const bf16_t* _s = ((isA) ? gA : gB) + (size_t)(h) * 131072 + (kt1) * 64;  \
    char* _l = smw + (bufb) * 65536 + ((isA) ? 0 : 32768) + (h) * 16384;       \
    __builtin_amdgcn_global_load_lds((const GLOBAL_AS void*)_s,                \
                                     (LDS_AS void*)_l, 16, 0, 0);              \
    __builtin_amdgcn_global_load_lds((const GLOBAL_AS void*)(_s + 65536),      \
                                     (LDS_AS void*)(_l + 8192), 16, 0, 0);     \
} while (0)

#define RD_A(bufb, mhh) do {                                                   \
    _Pragma("unroll") for (int mi = 0; mi < 2; ++mi) {                         \
      const int rr = wmq * 32 + mi * 16 + lane15;                              \
      const char* _p = sm + (bufb) * 65536 + (mhh) * 16384 + rr * 128;         \
      const int sz = (rr & 7) << 4;                                            \
      _Pragma("unroll") for (int kk = 0; kk < 2; ++kk)                         \
        afr[mhh][mi][kk] = *reinterpret_cast<const bf16x8*>(_p + ((kk * 64 + g16) ^ sz)); \
    } } while (0)

#define RD_B(bufb, nhh) do {                                                   \
    _Pragma("unroll") for (int ni = 0; ni < 4; ++ni) {                         \
      const int rr = wnq * 64 + ni * 16 + lane15;                              \
      const char* _p = sm + (bufb) * 65536 + 32768 + (nhh) * 16384 + rr * 128; \
      const int sz = (rr & 7) << 4;                                            \
      _Pragma("unroll") for (int kk = 0; kk < 2; ++kk)                         \
        bfr[ni][kk] = *reinterpret_cast<const bf16x8*>(_p + ((kk * 64 + g16) ^ sz)); \
    } } while (0)

#define MM(MH, NH) do {                                                        \
    __builtin_amdgcn_s_setprio(1);                                             \
    _Pragma("unroll") for (int kk = 0; kk < 2; ++kk)                           \
    _Pragma("unroll") for (int mi = 0; mi < 2; ++mi)                           \
    _Pragma("unroll") for (int ni = 0; ni < 4; ++ni)                           \
      acc[MH][mi][NH][ni] = __builtin_amdgcn_mfma_f32_16x16x32_bf16(           \
          afr[MH][mi][kk], bfr[ni][kk], acc[MH][mi][NH][ni], 0, 0, 0);         \
    __builtin_amdgcn_s_setprio(0);                                             \
} while (0)

#define BARM() asm volatile("s_barrier" ::: "memory")

    // prologue: stage all 4 halves of tile 0 (issue order A0,B0,A1,B1)
    STAGE(0, 1, 0, 0);
    STAGE(0, 0, 0, 0);
    STAGE(0, 1, 1, 0);
    STAGE(0, 0, 1, 0);
    asm volatile("s_waitcnt vmcnt(4)" ::: "memory");   // A0,B0 done
    BARM();

#pragma unroll 2
    for (int t = 0; t < 16; ++t) {
        const int buf = t & 1;
        const bool pf = t < 15;
        const int k1 = t + 1;
        // ---- P0: A0 x B0; stage A0(t+1)
        RD_A(buf, 0); RD_B(buf, 0);
        if (pf) STAGE(buf ^ 1, 1, 0, k1);
        __builtin_amdgcn_s_barrier();
        MM(0, 0);
        if (pf) { asm volatile("s_waitcnt vmcnt(4)" ::: "memory"); }   // A1(t) done
        else    { asm volatile("s_waitcnt vmcnt(2)" ::: "memory"); }
        BARM();
        // ---- P1: A1 x B0; stage B0(t+1)
        RD_A(buf, 1);
        if (pf) STAGE(buf ^ 1, 0, 0, k1);
        __builtin_amdgcn_s_barrier();
        MM(1, 0);
        if (pf) { asm volatile("s_waitcnt vmcnt(4)" ::: "memory"); }   // B1(t) done
        else    { asm volatile("s_waitcnt vmcnt(0)" ::: "memory"); }
        BARM();
        // ---- P2: A1 x B1; stage A1(t+1)
        RD_B(buf, 1);
        if (pf) STAGE(buf ^ 1, 1, 1, k1);
        __builtin_amdgcn_s_barrier();
        MM(1, 1);
        BARM();
        // ---- P3: A0 x B1 (A0 frags persist, B1 frags persist — no ds_reads)
        if (pf) STAGE(buf ^ 1, 0, 1, k1);
        __builtin_amdgcn_s_barrier();
        MM(0, 1);
        if (pf) { asm volatile("s_waitcnt vmcnt(4)" ::: "memory"); }   // A0,B0(t+1) done
        BARM();
    }

    // C-write. n<1024 -> xf[m,n]; n>=1024 -> xb[m-1,n-1024] (skip m==0).
    const bool isF  = bcol < 4;           // block-uniform
    const int rbase = brow * 256 + wmq * 32 + (lane >> 4) * 4;
    const int cb0   = bcol * 256 + wnq * 64 + lane15;
    #pragma unroll
    for (int mh = 0; mh < 2; ++mh)
    #pragma unroll
    for (int mi = 0; mi < 2; ++mi)
    #pragma unroll
    for (int j = 0; j < 4; ++j) {
        const int r = rbase + mh * 128 + mi * 16 + j;
        #pragma unroll
        for (int nh = 0; nh < 2; ++nh)
        #pragma unroll
        for (int ni = 0; ni < 4; ++ni) {
            const int c = cb0 + nh * 128 + ni * 16;
            const __bf16 v = (__bf16)acc[mh][mi][nh][ni][j];
            if (isF)         xf[(size_t)r * 1024 + c] = v;
            else if (r >= 1) xb[(size_t)(r - 1) * 1024 + (c - 1024)] = v;
        }
    }
#undef STAGE
#undef RD_A
#undef RD_B
#undef MM
#undef BARM
}

// ---------------- epilogue: TWO rows per wave (ILP), bf16 u ------------------
__global__ __launch_bounds__(256) void k_epi(const bf16_t* __restrict__ u16,
                                             const bf16_t* __restrict__ xf,
                                             const bf16_t* __restrict__ xb,
                                             const float* __restrict__ w1,
                                             const float* __restrict__ w2,
                                             const float* __restrict__ bb,
                                             const float* __restrict__ Wc,
                                             float* __restrict__ y,
                                             float* __restrict__ gout,
                                             float* __restrict__ fout) {
    const int lane = threadIdx.x & 63;
    const int r0   = blockIdx.x * 8 + (threadIdx.x >> 6) * 2;   // rows r0, r0+1

    // issue all 12 vector loads first
    bf16x8 u8[2][2], f8[2][2], b8[2][2];
    #pragma unroll
    for (int rr = 0; rr < 2; ++rr) {
        const size_t rb = (size_t)(r0 + rr) * Dd;
        #pragma unroll
        for (int j = 0; j < 2; ++j) {
            const int e = j * 512 + lane * 8;
            u8[rr][j] = *reinterpret_cast<const bf16x8*>(u16 + rb + e);
            f8[rr][j] = *reinterpret_cast<const bf16x8*>(xf + rb + e);
            b8[rr][j] = *reinterpret_cast<const bf16x8*>(xb + rb + e);
        }
    }
    float w1v[16], w2v[16], wcv[16];
    #pragma unroll
    for (int j = 0; j < 2; ++j) {
        const int e = j * 512 + lane * 8;
        #pragma unroll
        for (int i = 0; i < 8; ++i) {
            w1v[j*8+i] = w1[e + i];
            w2v[j*8+i] = w2[e + i];
            wcv[j*8+i] = Wc[e + i];
        }
    }

    float uv[2][16], xfv[2][16], xbv[2][16];
    #pragma unroll
    for (int rr = 0; rr < 2; ++rr) {
        const int t = (r0 + rr) & (Tseq - 1);
        #pragma unroll
        for (int j = 0; j < 2; ++j) {
            #pragma unroll
            for (int i = 0; i < 8; ++i) {
                uv[rr][j*8+i]  = (float)u8[rr][j][i];
                xfv[rr][j*8+i] = (float)f8[rr][j][i];
                xbv[rr][j*8+i] = (float)b8[rr][j][i];
            }
        }
        if (t == 0) {
            #pragma unroll
            for (int i = 0; i < 16; ++i) xfv[rr][i] = uv[rr][i];
        }
        if (t == Tseq - 1) {
            #pragma unroll
            for (int i = 0; i < 16; ++i) xbv[rr][i] = uv[rr][i];
        }
    }

    float part[2] = {0.0f, 0.0f};
    #pragma unroll
    for (int rr = 0; rr < 2; ++rr)
        #pragma unroll
        for (int i = 0; i < 16; ++i)
            part[rr] += xfv[rr][i] * w1v[i] + xbv[rr][i] * w2v[i];
    #pragma unroll
    for (int off = 32; off >= 1; off >>= 1) {
        part[0] += __shfl_xor(part[0], off);
        part[1] += __shfl_xor(part[1], off);
    }
    const float bias = bb[0];
    float g[2];
    g[0] = 1.0f / (1.0f + __expf(-(part[0] + bias)));
    g[1] = 1.0f / (1.0f + __expf(-(part[1] + bias)));

    float p2[2] = {0.0f, 0.0f};
    #pragma unroll
    for (int rr = 0; rr < 2; ++rr) {
        const size_t rb = (size_t)(r0 + rr) * Dd;
        #pragma unroll
        for (int j = 0; j < 4; ++j) {          // 4 x float4 stores per row
            float4 yv;
            const int e = (j >> 1) * 512 + lane * 8 + (j & 1) * 4;
            const int q = (j >> 1) * 8 + (j & 1) * 4;
            yv.x = g[rr] * (xfv[rr][q+0] + xbv[rr][q+0]) + (1.0f - g[rr]) * uv[rr][q+0];
            yv.y = g[rr] * (xfv[rr][q+1] + xbv[rr][q+1]) + (1.0f - g[rr]) * uv[rr][q+1];
            yv.z = g[rr] * (xfv[rr][q+2] + xbv[rr][q+2]) + (1.0f - g[rr]) * uv[rr][q+2];
            yv.w = g[rr] * (xfv[rr][q+3] + xbv[rr][q+3]) + (1.0f - g[rr]) * uv[rr][q+3];
            *reinterpret_cast<float4*>(y + rb + e) = yv;
            p2[rr] += yv.x * wcv[q+0] + yv.y * wcv[q+1] + yv.z * wcv[q+2] + yv.w * wcv[q+3];
        }
    }
    #pragma unroll
    for (int off = 32; off >= 1; off >>= 1) {
        p2[0] += __shfl_xor(p2[0], off);
        p2[1] += __shfl_xor(p2[1], off);
    }
    if (lane == 0) {
        gout[r0]     = g[0];
        gout[r0 + 1] = g[1];
        fout[r0]     = 1.0f / (1.0f + __expf(-p2[0]));
        fout[r0 + 1] = 1.0f / (1.0f + __expf(-p2[1]));
    }
}

extern "C" void kernel_launch(void* const* d_in, const int* in_sizes, int n_in,
                              void* d_out, int out_size, void* d_ws, size_t ws_size,
                              hipStream_t stream) {
    const float* u   = (const float*)d_in[0];
    const float* WB  = (const float*)d_in[2];
    const float* WBf = (const float*)d_in[4];
    const float* w1  = (const float*)d_in[5];
    const float* w2  = (const float*)d_in[6];
    const float* bb  = (const float*)d_in[7];
    const float* Wc  = (const float*)d_in[8];

    char* ws = (char*)d_ws;
    bf16_t* u16  = (bf16_t*)(ws);                         //  64 MiB
    bf16_t* wcat = (bf16_t*)(ws + 67108864);              //   4 MiB
    bf16_t* xfw  = (bf16_t*)(ws + 71303168);              //  64 MiB
    bf16_t* xbw  = (bf16_t*)(ws + 138412032);             //  64 MiB

    float* y    = (float*)d_out;
    float* gout = y + (size_t)Mrows * Dd;
    float* fout = gout + Mrows;

    // fused casts: 8388608 u-groups + 524288 w-groups = 8912896 -> 34816 blocks
    k_prep<<<dim3(34816), dim3(256), 0, stream>>>(u, WB, WBf, u16, wcat);

    // (M/256)*(Ncat/256) = 128*8 = 1024 blocks, 512 threads
    k_gemm<<<dim3(1024), dim3(512), 0, stream>>>(u16, wcat, xfw, xbw);

    // two rows per wave, 8 rows per block
    k_epi<<<dim3(Mrows / 8), dim3(256), 0, stream>>>(u16, xfw, xbw, w1, w2, bb, Wc,
                                                     y, gout, fout);
}